// Round 5
// baseline (48.754 us; speedup 1.0000x reference)
//
#include <hip/hip_runtime.h>

#define NCLS   80
#define NA     9
#define NH     64
#define NW     64
#define NB     8
#define NGT    32
#define NANCH  (NA * NH * NW)            // 36864 anchors per image
#define A_PER_WAVE 32
#define WAVES_PER_IMG (NANCH / A_PER_WAVE)   // 1152
#define NTHR   256
#define WPB    4                              // waves per block
#define NBLK   (NB * WAVES_PER_IMG / WPB)     // 2304
#define BLKS_PER_IMG (WAVES_PER_IMG / WPB)    // 288
#define KI     10                             // float4 logit loads per lane (640 f4 / 64 lanes)
#define NWAVE  (NB * WAVES_PER_IMG)           // 9216 total waves

// Anchor W/H computed in double (matches Python float arithmetic), cast to f32.
__device__ __constant__ float c_aw[9] = {
    (float)(32.0 * 1.0    * 1.0), (float)(32.0 * 1.0    * 1.4), (float)(32.0 * 1.0    * 0.7),
    (float)(32.0 * 1.2599 * 1.0), (float)(32.0 * 1.2599 * 1.4), (float)(32.0 * 1.2599 * 0.7),
    (float)(32.0 * 1.5874 * 1.0), (float)(32.0 * 1.5874 * 1.4), (float)(32.0 * 1.5874 * 0.7)};
__device__ __constant__ float c_ah[9] = {
    (float)(32.0 * 1.0    * 1.0), (float)(32.0 * 1.0    * 0.7), (float)(32.0 * 1.0    * 1.4),
    (float)(32.0 * 1.2599 * 1.0), (float)(32.0 * 1.2599 * 0.7), (float)(32.0 * 1.2599 * 1.4),
    (float)(32.0 * 1.5874 * 1.0), (float)(32.0 * 1.5874 * 0.7), (float)(32.0 * 1.5874 * 1.4)};

// One float4 partial per wave: {cls_loss, xywh_loss, pos_count, 0}
__global__ __launch_bounds__(NTHR) void retina_main(
    const float* __restrict__ t_xywh,      // [B, N, 4]
    const float* __restrict__ cls_logits,  // [B, N, 80]
    const float* __restrict__ gt_bboxes,   // [B, 32, 4] cxcywh
    const int*   __restrict__ gt_cats,     // [B, 32]
    float4* __restrict__ part)             // [NWAVE]
{
    const int tid = threadIdx.x;
    const int l   = tid & 63;                       // lane
    const int gw  = blockIdx.x * WPB + (tid >> 6);  // global wave id
    const int b   = blockIdx.x / BLKS_PER_IMG;      // image (blocks never span images)
    const int la0 = l & 31;                         // this lane's anchor within the wave

    // ---- issue ALL 10 coalesced logit loads first; everything below hides them ----
    const float4* base = (const float4*)cls_logits + (size_t)gw * (A_PER_WAVE * NCLS / 4);
    float4 xb[KI];
#pragma unroll
    for (int k = 0; k < KI; ++k) xb[k] = base[k * 64 + l];

    // ---- per-lane anchor geometry (lanes 32-63 duplicate lanes 0-31; no divergence) ----
    const int n  = (gw % WAVES_PER_IMG) * A_PER_WAVE + la0;  // anchor within image
    const int a  = n >> 12;
    const int hy = (n >> 6) & 63;
    const int wx = n & 63;
    const float acx = (wx + 0.5f) * 8.0f;
    const float acy = (hy + 0.5f) * 8.0f;
    const float aw  = c_aw[a];
    const float ah  = c_ah[a];

    // ---- IoU vs 32 GTs (wave-uniform scalar GT loads), bit-exact vs numpy ----
    const float4* gt4  = (const float4*)gt_bboxes + b * NGT;
    const int*    gcat = gt_cats + b * NGT;
    float  best = -1.0f;
    int    bestcat = 0;
    float4 bgt = gt4[0];
    {
#pragma clang fp contract(off)
        const float a_tlx = acx - aw * 0.5f, a_tly = acy - ah * 0.5f;
        const float a_brx = acx + aw * 0.5f, a_bry = acy + ah * 0.5f;
        const float area_a = aw * ah;
        for (int gg = 0; gg < NGT; ++gg) {
            const float4 gb = gt4[gg];          // uniform -> s_load
            const float g_tlx = gb.x - gb.z * 0.5f, g_tly = gb.y - gb.w * 0.5f;
            const float g_brx = gb.x + gb.z * 0.5f, g_bry = gb.y + gb.w * 0.5f;
            float dx = fminf(a_brx, g_brx) - fmaxf(a_tlx, g_tlx);
            float dy = fminf(a_bry, g_bry) - fmaxf(a_tly, g_tly);
            dx = fmaxf(dx, 0.0f);
            dy = fmaxf(dy, 0.0f);
            const float inter = dx * dy;
            const float area_g = gb.z * gb.w;
            const float uni = area_a + area_g - inter;   // no fma
            const float iou = inter / uni;
            if (iou > best) {                    // strict > = first argmax
                best = iou; bestcat = gcat[gg]; bgt = gb;
            }
        }
    }

    const bool pos = best > 0.5f;
    const bool neg = best < 0.4f;
    const int  f   = (pos | neg) ? (pos ? bestcat : 256) : -1;  // reg-resident flag

    // ---- xywh loss (lanes<32 only, positives only — rare) ----
    float lx = 0.0f, pcnt = 0.0f;
    if (pos && l < 32) {
        pcnt = 1.0f;
        const float4 t = ((const float4*)t_xywh)[(size_t)gw * A_PER_WAVE + la0];
        const float tx = (bgt.x - acx) / aw;
        const float ty = (bgt.y - acy) / ah;
        const float tw = logf(bgt.z / aw + 1e-8f);
        const float th = logf(bgt.w / ah + 1e-8f);
        const float d0 = t.x - tx, d1 = t.y - ty, d2 = t.z - tw, d3 = t.w - th;
        lx = d0 * d0 + d1 * d1 + d2 * d2 + d3 * d3;
    }

    // ---- BCE from prefetched registers; flags via in-wave shuffle, no LDS/barrier ----
    float lc = 0.0f;
#pragma unroll
    for (int k = 0; k < KI; ++k) {
        const int e  = k * 64 + l;           // f4 index within wave chunk [0,640)
        const int la = e / 20;               // owning local anchor [0,32)
        const int c0 = (e - la * 20) * 4;    // starting class of this f4
        const int fl = __shfl(f, la);        // flag lives in lane la's register
        const float4 x = xb[k];
        const float m = (fl >= 0) ? 1.0f : 0.0f;
        float sp4;
        {
            const float s0 = fmaxf(x.x, 0.0f) + __logf(1.0f + __expf(-fabsf(x.x)));
            const float s1 = fmaxf(x.y, 0.0f) + __logf(1.0f + __expf(-fabsf(x.y)));
            const float s2 = fmaxf(x.z, 0.0f) + __logf(1.0f + __expf(-fabsf(x.z)));
            const float s3 = fmaxf(x.w, 0.0f) + __logf(1.0f + __expf(-fabsf(x.w)));
            sp4 = (s0 + s1) + (s2 + s3);
        }
        lc += m * sp4;
        // one-hot correction: only positive anchors (rare) — wave-level skip
        if (__any(fl >= 0 && fl < NCLS)) {
            lc -= (fl == c0    ) ? x.x : 0.0f;
            lc -= (fl == c0 + 1) ? x.y : 0.0f;
            lc -= (fl == c0 + 2) ? x.z : 0.0f;
            lc -= (fl == c0 + 3) ? x.w : 0.0f;
        }
    }

    // ---- wave reduction; lane 0 stores one float4 partial ----
    float v0 = lc, v1 = lx, v2 = pcnt;
    for (int o = 32; o > 0; o >>= 1) {
        v0 += __shfl_down(v0, o);
        v1 += __shfl_down(v1, o);
        v2 += __shfl_down(v2, o);
    }
    if (l == 0) part[gw] = make_float4(v0, v1, v2, 0.0f);
}

// ---- fold 9216 wave partials into the scalar loss ----
__global__ __launch_bounds__(256) void retina_final(
    const float4* __restrict__ part, float* __restrict__ out)
{
    __shared__ float s_lc[NB], s_pc[NB], s_lx[4];
    const int tid = threadIdx.x;
    const int b = tid >> 5, l = tid & 31;    // 32 lanes per image

    float lc = 0.0f, pc = 0.0f, lx = 0.0f;
    for (int i = l; i < WAVES_PER_IMG; i += 32) {
        const float4 p = part[b * WAVES_PER_IMG + i];
        lc += p.x; lx += p.y; pc += p.z;
    }
    for (int o = 16; o > 0; o >>= 1) {       // xor butterfly stays within the 32-group
        lc += __shfl_xor(lc, o);
        pc += __shfl_xor(pc, o);
    }
    if (l == 0) { s_lc[b] = lc; s_pc[b] = pc; }

    for (int o = 32; o > 0; o >>= 1) lx += __shfl_down(lx, o);
    if ((tid & 63) == 0) s_lx[tid >> 6] = lx;
    __syncthreads();

    if (tid == 0) {
        const float lxt = s_lx[0] + s_lx[1] + s_lx[2] + s_lx[3];
        float s = 0.0f;
        for (int bb = 0; bb < NB; ++bb)
            s += s_lc[bb] / (s_pc[bb] + 1.0f);
        out[0] = (lxt + s) / (float)NB;
    }
}

extern "C" void kernel_launch(void* const* d_in, const int* in_sizes, int n_in,
                              void* d_out, int out_size, void* d_ws, size_t ws_size,
                              hipStream_t stream)
{
    const float* t_xywh     = (const float*)d_in[0];
    const float* cls_logits = (const float*)d_in[1];
    const float* gt_bboxes  = (const float*)d_in[2];
    const int*   gt_cats    = (const int*)d_in[3];

    float4* part = (float4*)d_ws;   // 9216 * 16 B = 147 KB

    retina_main<<<NBLK, NTHR, 0, stream>>>(t_xywh, cls_logits, gt_bboxes, gt_cats, part);
    retina_final<<<1, 256, 0, stream>>>(part, (float*)d_out);
}

// Round 6
// 34.399 us; speedup vs baseline: 1.4173x; 1.4173x over previous
//
#include <hip/hip_runtime.h>

#define NCLS   80
#define NB     8
#define NGT    32
#define NANCH  36864                 // anchors per image (9*64*64)
#define NTHR   256                   // threads per block = anchors per block
#define NBLK   1152                  // (8 * 36864) / 256
#define BLKS_PER_IMG 144
#define KI     10                    // float4 per thread per 128-anchor half-chunk

// Anchor W/H computed in double (matches Python float arithmetic), cast to f32.
__device__ __constant__ float c_aw[9] = {
    (float)(32.0 * 1.0    * 1.0), (float)(32.0 * 1.0    * 1.4), (float)(32.0 * 1.0    * 0.7),
    (float)(32.0 * 1.2599 * 1.0), (float)(32.0 * 1.2599 * 1.4), (float)(32.0 * 1.2599 * 0.7),
    (float)(32.0 * 1.5874 * 1.0), (float)(32.0 * 1.5874 * 1.4), (float)(32.0 * 1.5874 * 0.7)};
__device__ __constant__ float c_ah[9] = {
    (float)(32.0 * 1.0    * 1.0), (float)(32.0 * 1.0    * 0.7), (float)(32.0 * 1.0    * 1.4),
    (float)(32.0 * 1.2599 * 1.0), (float)(32.0 * 1.2599 * 0.7), (float)(32.0 * 1.2599 * 1.4),
    (float)(32.0 * 1.5874 * 1.0), (float)(32.0 * 1.5874 * 0.7), (float)(32.0 * 1.5874 * 1.4)};

#define LOG2E 1.4426950408889634f
#define LN2   0.6931471805599453f

// BCE over one 128-anchor chunk held in registers. Accumulates lmax, l2, hot.
#define BCE_CHUNK(XB, OFF)                                                      \
    _Pragma("unroll")                                                           \
    for (int k = 0; k < KI; ++k) {                                              \
        const int e  = k * NTHR + tid;                                          \
        const int la = e / 20;                                                  \
        const int c0 = (e - la * 20) * 4;                                       \
        const int fl = s_flag[(OFF) + la];                                      \
        const float4 x = XB[k];                                                 \
        const float m = (fl >= 0) ? 1.0f : 0.0f;                                \
        const float t0 = __builtin_amdgcn_exp2f(fabsf(x.x) * -LOG2E);           \
        const float t1 = __builtin_amdgcn_exp2f(fabsf(x.y) * -LOG2E);           \
        const float t2 = __builtin_amdgcn_exp2f(fabsf(x.z) * -LOG2E);           \
        const float t3 = __builtin_amdgcn_exp2f(fabsf(x.w) * -LOG2E);           \
        const float g0 = __builtin_amdgcn_logf(1.0f + t0);                      \
        const float g1 = __builtin_amdgcn_logf(1.0f + t1);                      \
        const float g2 = __builtin_amdgcn_logf(1.0f + t2);                      \
        const float g3 = __builtin_amdgcn_logf(1.0f + t3);                      \
        l2   += m * ((g0 + g1) + (g2 + g3));                                    \
        lmax += m * ((fmaxf(x.x, 0.0f) + fmaxf(x.y, 0.0f)) +                    \
                     (fmaxf(x.z, 0.0f) + fmaxf(x.w, 0.0f)));                    \
        if (__any(fl >= 0 && fl < NCLS)) {   /* positive anchors are rare */    \
            hot += (fl == c0    ) ? x.x : 0.0f;                                 \
            hot += (fl == c0 + 1) ? x.y : 0.0f;                                 \
            hot += (fl == c0 + 2) ? x.z : 0.0f;                                 \
            hot += (fl == c0 + 3) ? x.w : 0.0f;                                 \
        }                                                                       \
    }

// One float4 partial per block: {cls_loss, xywh_loss, pos_count, 0}
__global__ __launch_bounds__(NTHR, 4) void retina_main(
    const float* __restrict__ t_xywh,      // [B, N, 4]
    const float* __restrict__ cls_logits,  // [B, N, 80]
    const float* __restrict__ gt_bboxes,   // [B, 32, 4] cxcywh
    const int*   __restrict__ gt_cats,     // [B, 32]
    float4* __restrict__ part)             // [NBLK]
{
    __shared__ int   s_flag[NTHR];
    __shared__ float s_red[4 * 3];

    const int tid = threadIdx.x;
    const int blk = blockIdx.x;
    const int b   = blk / BLKS_PER_IMG;

    // ---- prefetch ALL 20 float4 of this block's 80 KB logit slice first ----
    const float4* baseA = (const float4*)cls_logits + (size_t)blk * (NTHR * NCLS / 4);
    const float4* baseB = baseA + (NTHR * NCLS / 8);
    float4 xa[KI], xbv[KI];
#pragma unroll
    for (int k = 0; k < KI; ++k) xa[k]  = baseA[k * NTHR + tid];
#pragma unroll
    for (int k = 0; k < KI; ++k) xbv[k] = baseB[k * NTHR + tid];

    // ---- anchor geometry: thread tid owns anchor tid of this block ----
    const int n  = (blk % BLKS_PER_IMG) * NTHR + tid;  // anchor within image
    const int a  = n >> 12;
    const int hy = (n >> 6) & 63;
    const int wx = n & 63;
    const float acx = (wx + 0.5f) * 8.0f;
    const float acy = (hy + 0.5f) * 8.0f;
    const float aw  = c_aw[a];
    const float ah  = c_ah[a];

    // ---- IoU vs 32 GTs (wave-uniform scalar GT loads), bit-exact vs numpy ----
    const float4* gt4  = (const float4*)gt_bboxes + b * NGT;
    const int*    gcat = gt_cats + b * NGT;
    float best = -1.0f;
    int   bi   = 0;
    {
#pragma clang fp contract(off)
        const float a_tlx = acx - aw * 0.5f, a_tly = acy - ah * 0.5f;
        const float a_brx = acx + aw * 0.5f, a_bry = acy + ah * 0.5f;
        const float area_a = aw * ah;
        for (int gg = 0; gg < NGT; ++gg) {
            const float4 gb = gt4[gg];               // uniform -> s_load
            const float g_tlx = gb.x - gb.z * 0.5f, g_tly = gb.y - gb.w * 0.5f;
            const float g_brx = gb.x + gb.z * 0.5f, g_bry = gb.y + gb.w * 0.5f;
            float dx = fminf(a_brx, g_brx) - fmaxf(a_tlx, g_tlx);
            float dy = fminf(a_bry, g_bry) - fmaxf(a_tly, g_tly);
            dx = fmaxf(dx, 0.0f);
            dy = fmaxf(dy, 0.0f);
            const float inter = dx * dy;
            const float area_g = gb.z * gb.w;
            const float uni = area_a + area_g - inter;   // no fma
            const float iou = inter / uni;
            if (iou > best) { best = iou; bi = gg; }     // strict > = first argmax
        }
    }

    const bool pos = best > 0.5f;
    const bool neg = best < 0.4f;
    int f = (pos | neg) ? 256 : -1;

    // ---- xywh loss: positives only (rare); gather matched GT lazily ----
    float lx = 0.0f, pcnt = 0.0f;
    if (pos) {
        f    = gcat[bi];                      // per-lane gather, rare lanes
        pcnt = 1.0f;
        const float4 g = gt4[bi];
        const float4 t = ((const float4*)t_xywh)[(size_t)blk * NTHR + tid];
        const float tx = (g.x - acx) / aw;
        const float ty = (g.y - acy) / ah;
        const float tw = logf(g.z / aw + 1e-8f);
        const float th = logf(g.w / ah + 1e-8f);
        const float d0 = t.x - tx, d1 = t.y - ty, d2 = t.z - tw, d3 = t.w - th;
        lx = d0 * d0 + d1 * d1 + d2 * d2 + d3 * d3;
    }
    s_flag[tid] = f;
    __syncthreads();

    // ---- BCE over both register-resident chunks ----
    float l2 = 0.0f, lmax = 0.0f, hot = 0.0f;
    BCE_CHUNK(xa, 0)
    BCE_CHUNK(xbv, 128)
    const float lc = lmax + LN2 * l2 - hot;

    // ---- block reduction of (lc, lx, pcnt) ----
    float v0 = lc, v1 = lx, v2 = pcnt;
    for (int o = 32; o > 0; o >>= 1) {
        v0 += __shfl_down(v0, o);
        v1 += __shfl_down(v1, o);
        v2 += __shfl_down(v2, o);
    }
    const int wave = tid >> 6;
    if ((tid & 63) == 0) {
        s_red[wave * 3 + 0] = v0;
        s_red[wave * 3 + 1] = v1;
        s_red[wave * 3 + 2] = v2;
    }
    __syncthreads();
    if (tid == 0) {
        float c = 0.0f, xw = 0.0f, pc = 0.0f;
        for (int w2 = 0; w2 < 4; ++w2) {
            c  += s_red[w2 * 3 + 0];
            xw += s_red[w2 * 3 + 1];
            pc += s_red[w2 * 3 + 2];
        }
        part[blk] = make_float4(c, xw, pc, 0.0f);
    }
}

// ---- fold 1152 block partials into the scalar loss ----
__global__ __launch_bounds__(256) void retina_final(
    const float4* __restrict__ part, float* __restrict__ out)
{
    __shared__ float s_lc[NB], s_pc[NB], s_lx[NB];
    const int tid = threadIdx.x;
    const int b = tid >> 5, l = tid & 31;    // 32 lanes per image

    float lc = 0.0f, lx = 0.0f, pc = 0.0f;
    for (int i = l; i < BLKS_PER_IMG; i += 32) {
        const float4 p = part[b * BLKS_PER_IMG + i];
        lc += p.x; lx += p.y; pc += p.z;
    }
    for (int o = 16; o > 0; o >>= 1) {       // xor butterfly stays within the 32-group
        lc += __shfl_xor(lc, o);
        lx += __shfl_xor(lx, o);
        pc += __shfl_xor(pc, o);
    }
    if (l == 0) { s_lc[b] = lc; s_pc[b] = pc; s_lx[b] = lx; }
    __syncthreads();

    if (tid == 0) {
        float s = 0.0f, lxt = 0.0f;
        for (int bb = 0; bb < NB; ++bb) {
            lxt += s_lx[bb];
            s   += s_lc[bb] / (s_pc[bb] + 1.0f);
        }
        out[0] = (lxt + s) / (float)NB;
    }
}

extern "C" void kernel_launch(void* const* d_in, const int* in_sizes, int n_in,
                              void* d_out, int out_size, void* d_ws, size_t ws_size,
                              hipStream_t stream)
{
    const float* t_xywh     = (const float*)d_in[0];
    const float* cls_logits = (const float*)d_in[1];
    const float* gt_bboxes  = (const float*)d_in[2];
    const int*   gt_cats    = (const int*)d_in[3];

    float4* part = (float4*)d_ws;   // 1152 * 16 B = 18.4 KB

    retina_main<<<NBLK, NTHR, 0, stream>>>(t_xywh, cls_logits, gt_bboxes, gt_cats, part);
    retina_final<<<1, 256, 0, stream>>>(part, (float*)d_out);
}